// Round 1
// baseline (895.365 us; speedup 1.0000x reference)
//
#include <hip/hip_runtime.h>
#include <hip/hip_bf16.h>

// Problem constants (B=64, S=4096, H=256, 2H=512, OUT=24)
#define B_   64
#define S_   4096
#define H_   256
#define K2H_ 512
#define OUT_ 24

typedef __attribute__((ext_vector_type(4))) float f32x4;
typedef __attribute__((ext_vector_type(2))) float f32x2;
typedef __attribute__((ext_vector_type(4))) unsigned short u16x4;
typedef __attribute__((ext_vector_type(8))) unsigned short u16x8;
typedef __attribute__((ext_vector_type(8))) short bf16x8;

__device__ __forceinline__ unsigned short f2bf(float x) {
    unsigned int u = __float_as_uint(x);
    unsigned int r = (u + 0x7FFFu + ((u >> 16) & 1u)) >> 16;  // RNE
    return (unsigned short)r;
}

// ---------------------------------------------------------------------------
// Kernel A (prep): blocks 0..63: q_term[b][n] = emb_ctxt[idx_c[b]] @ W_h + attn_b
//                  and emb_t gather. Blocks 64..127: W_e -> Bt bf16 transposed
//                  (Bt[n][k] = bf16(attn_W[256+k][n])), n-major for gemm_bt.
// ---------------------------------------------------------------------------
__global__ __launch_bounds__(256) void prep_kernel(
    const int* __restrict__ fut_ctxt, const int* __restrict__ fut_temp,
    const float* __restrict__ emb_ctxt, const float* __restrict__ emb_temp,
    const float* __restrict__ attn_W, const float* __restrict__ attn_b,
    float* __restrict__ qterm, float* __restrict__ embt,
    unsigned short* __restrict__ Bt)
{
    const int bid = blockIdx.x;
    const int t = threadIdx.x;
    if (bid < B_) {
        const int b  = bid;
        const int ic = fut_ctxt[b];
        const int it = fut_temp[b];
        const float* hq = emb_ctxt + (size_t)ic * H_;
        float acc = attn_b[t];
        for (int k = 0; k < H_; ++k)
            acc += hq[k] * attn_W[k * H_ + t];
        qterm[b * H_ + t] = acc;
        embt[b * H_ + t]  = emb_temp[(size_t)it * H_ + t];
    } else {
        const int j = bid - B_;
        #pragma unroll
        for (int q = 0; q < 4; ++q) {
            const int n = j * 4 + q;
            #pragma unroll
            for (int kk = 0; kk < 2; ++kk) {
                const int k = kk * 256 + t;
                Bt[(size_t)n * K2H_ + k] = f2bf(attn_W[(size_t)(H_ + k) * H_ + n]);
            }
        }
    }
}

// ---------------------------------------------------------------------------
// Kernel B (scores): fused  scores[b,s] = sum_h tanh(qterm[b,h] + enc[b,s,:]@W_e[:,h]) * v[h]
// Tile: 128 rows x 256 cols per block (4 waves x 32 rows), K-chunks of 64.
// A (enc rows) f32->bf16 staged into LDS; Bt staged per-chunk from L2.
// Both LDS tiles: 128B rows with byte ^= (row&7)<<4 swizzle (kills the
// 16-way phase conflict of stride-128B ds_read_b128).
// ---------------------------------------------------------------------------
#define BM_ 128
#define BK_ 64

__global__ __launch_bounds__(256, 2) void score_kernel(
    const float* __restrict__ enc, const unsigned short* __restrict__ Bt,
    const float* __restrict__ qterm, const float* __restrict__ vvec,
    float* __restrict__ scores)
{
    __shared__ __align__(16) unsigned char lds[16384 + 32768];  // As 16KB | Bs 32KB
    const int t    = threadIdx.x;
    const int wave = t >> 6;
    const int lane = t & 63;
    const int l15  = lane & 15;
    const int lg   = lane >> 4;
    const int row0 = blockIdx.x * BM_;
    const int b    = row0 >> 12;   // /S_

    f32x4 acc[2][16];
    #pragma unroll
    for (int rt = 0; rt < 2; ++rt)
        #pragma unroll
        for (int ct = 0; ct < 16; ++ct)
            acc[rt][ct] = (f32x4){0.f, 0.f, 0.f, 0.f};

    for (int kc = 0; kc < 8; ++kc) {
        __syncthreads();
        // --- stage A: 128 rows x 64 k, f32 -> bf16, swizzled ---
        #pragma unroll
        for (int i = 0; i < 8; ++i) {
            const int idx = i * 1024 + t * 4;
            const int r = idx >> 6;
            const int c = idx & 63;
            f32x4 a = *(const f32x4*)(enc + (size_t)(row0 + r) * K2H_ + kc * BK_ + c);
            u16x4 h = { f2bf(a.x), f2bf(a.y), f2bf(a.z), f2bf(a.w) };
            const unsigned off = (unsigned)r * 128u +
                                 (((unsigned)c * 2u) ^ (((unsigned)r & 7u) << 4));
            *(u16x4*)(lds + off) = h;
        }
        // --- stage B: 256 n x 64 k bf16 from global Bt (L2-resident), swizzled ---
        #pragma unroll
        for (int i = 0; i < 8; ++i) {
            const int idx = i * 256 + t;
            const int n = idx >> 3;
            const int g = idx & 7;
            u16x8 bb = *(const u16x8*)(Bt + (size_t)n * K2H_ + kc * BK_ + g * 8);
            const unsigned off = 16384u + (unsigned)n * 128u +
                                 (((unsigned)g * 16u) ^ (((unsigned)n & 7u) << 4));
            *(u16x8*)(lds + off) = bb;
        }
        __syncthreads();
        // --- compute: 2 k-steps of 32, 16 col-tiles, 2 row-tiles/wave ---
        #pragma unroll
        for (int kk2 = 0; kk2 < 2; ++kk2) {
            const unsigned kb = (unsigned)(kk2 * 64 + lg * 16);
            bf16x8 afr[2];
            #pragma unroll
            for (int rt = 0; rt < 2; ++rt) {
                const unsigned ar = (unsigned)(wave * 32 + rt * 16 + l15);
                afr[rt] = *(const bf16x8*)(lds + ar * 128u + (kb ^ ((ar & 7u) << 4)));
            }
            #pragma unroll
            for (int ct = 0; ct < 16; ++ct) {
                const unsigned nr = (unsigned)(ct * 16 + l15);
                bf16x8 bfr = *(const bf16x8*)(lds + 16384u + nr * 128u +
                                              (kb ^ ((nr & 7u) << 4)));
                acc[0][ct] = __builtin_amdgcn_mfma_f32_16x16x32_bf16(afr[0], bfr, acc[0][ct], 0, 0, 0);
                acc[1][ct] = __builtin_amdgcn_mfma_f32_16x16x32_bf16(afr[1], bfr, acc[1][ct], 0, 0, 0);
            }
        }
    }

    // --- epilogue: tanh + dot with v, reduce over the 16 col-lanes ---
    float p[2][4] = {};
    #pragma unroll
    for (int ct = 0; ct < 16; ++ct) {
        const int col = ct * 16 + l15;
        const float q  = qterm[b * H_ + col];
        const float vv = vvec[col];
        #pragma unroll
        for (int rt = 0; rt < 2; ++rt) {
            #pragma unroll
            for (int j = 0; j < 4; ++j) {
                const float e  = acc[rt][ct][j] + q;
                const float ex = __expf(2.0f * e);
                const float th = 1.0f - 2.0f / (ex + 1.0f);
                p[rt][j] += th * vv;
            }
        }
    }
    #pragma unroll
    for (int rt = 0; rt < 2; ++rt)
        #pragma unroll
        for (int j = 0; j < 4; ++j) {
            float s = p[rt][j];
            s += __shfl_xor(s, 1, 16);
            s += __shfl_xor(s, 2, 16);
            s += __shfl_xor(s, 4, 16);
            s += __shfl_xor(s, 8, 16);
            p[rt][j] = s;
        }
    if (l15 == 0) {
        #pragma unroll
        for (int rt = 0; rt < 2; ++rt) {
            const int rbase = row0 + wave * 32 + rt * 16 + lg * 4;
            #pragma unroll
            for (int j = 0; j < 4; ++j)
                scores[rbase + j] = p[rt][j];
        }
    }
}

// ---------------------------------------------------------------------------
// Kernel C: softmax over S per batch, in place.
// ---------------------------------------------------------------------------
__global__ __launch_bounds__(256) void softmax_kernel(float* __restrict__ scores)
{
    __shared__ float red[4];
    __shared__ float red2[4];
    const int b = blockIdx.x;
    const int t = threadIdx.x;
    const int wave = t >> 6, lane = t & 63;
    float* sp = scores + (size_t)b * S_;

    float loc[16];
    float m = -1e30f;
    #pragma unroll
    for (int i = 0; i < 16; ++i) {
        loc[i] = sp[i * 256 + t];
        m = fmaxf(m, loc[i]);
    }
    #pragma unroll
    for (int off = 32; off; off >>= 1) m = fmaxf(m, __shfl_xor(m, off, 64));
    if (lane == 0) red[wave] = m;
    __syncthreads();
    m = fmaxf(fmaxf(red[0], red[1]), fmaxf(red[2], red[3]));

    float sum = 0.f;
    #pragma unroll
    for (int i = 0; i < 16; ++i) {
        loc[i] = __expf(loc[i] - m);
        sum += loc[i];
    }
    #pragma unroll
    for (int off = 32; off; off >>= 1) sum += __shfl_xor(sum, off, 64);
    if (lane == 0) red2[wave] = sum;
    __syncthreads();
    sum = red2[0] + red2[1] + red2[2] + red2[3];
    const float inv = 1.0f / sum;
    #pragma unroll
    for (int i = 0; i < 16; ++i) sp[i * 256 + t] = loc[i] * inv;
}

// ---------------------------------------------------------------------------
// Kernel D: context partials.  partial[b][c][f] = sum_{s in chunk c} attn[b,s]*enc[b,s,f]
// Grid (64, 32); 256 threads, float2 per thread (f = 2t, 2t+1), 128 s-rows.
// ---------------------------------------------------------------------------
#define NSPLIT_ 32
__global__ __launch_bounds__(256) void context_kernel(
    const float* __restrict__ enc, const float* __restrict__ attn,
    float* __restrict__ partial)
{
    const int b = blockIdx.x;
    const int c = blockIdx.y;
    const int t = threadIdx.x;
    const int s0 = c * (S_ / NSPLIT_);
    const float* ep = enc + ((size_t)b * S_ + s0) * K2H_ + t * 2;
    const float* ap = attn + (size_t)b * S_ + s0;
    f32x2 acc = {0.f, 0.f};
    for (int s = 0; s < S_ / NSPLIT_; ++s) {
        const float w = ap[s];
        f32x2 e = *(const f32x2*)(ep + (size_t)s * K2H_);
        acc.x += w * e.x;
        acc.y += w * e.y;
    }
    *(f32x2*)(partial + ((size_t)b * NSPLIT_ + c) * K2H_ + t * 2) = acc;
}

// ---------------------------------------------------------------------------
// Kernel E: reduce partials -> context, GRU cell (h0 = 0), output head.
// One block per batch, 256 threads (= one hidden unit per thread).
// ---------------------------------------------------------------------------
__global__ __launch_bounds__(256) void final_kernel(
    const float* __restrict__ partial, const float* __restrict__ embt,
    const float* __restrict__ w_ih, const float* __restrict__ b_ih,
    const float* __restrict__ b_hh, const float* __restrict__ out_W,
    const float* __restrict__ out_b, float* __restrict__ d_out)
{
    __shared__ float x[3 * H_];
    __shared__ float hsh[H_];
    const int b = blockIdx.x;
    const int t = threadIdx.x;

    const float* pp = partial + (size_t)b * NSPLIT_ * K2H_;
    float c0 = 0.f, c1 = 0.f;
    #pragma unroll 4
    for (int c = 0; c < NSPLIT_; ++c) {
        c0 += pp[c * K2H_ + t];
        c1 += pp[c * K2H_ + H_ + t];
    }
    x[t]        = embt[b * H_ + t];  // emb_t
    x[H_ + t]   = c0;                // context[0:256]
    x[2*H_ + t] = c1;                // context[256:512]
    __syncthreads();

    float g0 = b_ih[t], g1 = b_ih[H_ + t], g2 = b_ih[2 * H_ + t];
    for (int k = 0; k < 3 * H_; ++k) {
        const float xv = x[k];
        const float* wrow = w_ih + (size_t)k * (3 * H_);
        g0 += xv * wrow[t];
        g1 += xv * wrow[H_ + t];
        g2 += xv * wrow[2 * H_ + t];
    }
    // gh = 0 @ w_hh + b_hh  (h0 == 0)
    const float r  = 1.0f / (1.0f + __expf(-(g0 + b_hh[t])));
    const float z  = 1.0f / (1.0f + __expf(-(g1 + b_hh[H_ + t])));
    const float ex = __expf(2.0f * (g2 + r * b_hh[2 * H_ + t]));
    const float n  = 1.0f - 2.0f / (ex + 1.0f);
    const float h  = (1.0f - z) * n;   // + z*h0 with h0=0

    d_out[B_ * OUT_ + b * H_ + t] = h; // second output: h[None] flattened
    hsh[t] = h;
    __syncthreads();

    if (t < 8 * OUT_) {
        const int o  = t >> 3;
        const int l8 = t & 7;
        float acc = 0.f;
        for (int k = l8; k < H_; k += 8)
            acc += hsh[k] * out_W[(size_t)k * OUT_ + o];
        #pragma unroll
        for (int off = 4; off; off >>= 1) acc += __shfl_xor(acc, off, 8);
        if (l8 == 0) d_out[b * OUT_ + o] = acc + out_b[o];
    }
}

// ---------------------------------------------------------------------------
extern "C" void kernel_launch(void* const* d_in, const int* in_sizes, int n_in,
                              void* d_out, int out_size, void* d_ws, size_t ws_size,
                              hipStream_t stream)
{
    const int*   fut_ctxt = (const int*)d_in[0];
    const int*   fut_temp = (const int*)d_in[1];
    const float* enc      = (const float*)d_in[2];
    const float* emb_ctxt = (const float*)d_in[3];
    const float* emb_temp = (const float*)d_in[4];
    const float* attn_W   = (const float*)d_in[5];
    const float* attn_b   = (const float*)d_in[6];
    const float* vvec     = (const float*)d_in[7];
    const float* w_ih     = (const float*)d_in[8];
    // d_in[9] = w_hh: unused since h0 == 0 (gh reduces to b_hh exactly)
    const float* b_ih     = (const float*)d_in[10];
    const float* b_hh     = (const float*)d_in[11];
    const float* out_W    = (const float*)d_in[12];
    const float* out_b    = (const float*)d_in[13];
    float* out = (float*)d_out;

    char* ws = (char*)d_ws;
    unsigned short* Bt = (unsigned short*)ws;                        // 256 KB bf16 W_e^T
    float* qterm   = (float*)(ws + (256u << 10));                    // 64 KB
    float* embt    = (float*)(ws + (320u << 10));                    // 64 KB
    float* scores  = (float*)(ws + (384u << 10));                    // 1 MB (scores -> attn in place)
    float* partial = (float*)(ws + (384u << 10) + (1024u << 10));    // 4 MB

    prep_kernel<<<128, 256, 0, stream>>>(fut_ctxt, fut_temp, emb_ctxt, emb_temp,
                                         attn_W, attn_b, qterm, embt, Bt);
    score_kernel<<<(B_ * S_) / BM_, 256, 0, stream>>>(enc, Bt, qterm, vvec, scores);
    softmax_kernel<<<B_, 256, 0, stream>>>(scores);
    dim3 gd(B_, NSPLIT_);
    context_kernel<<<gd, 256, 0, stream>>>(enc, scores, partial);
    final_kernel<<<B_, 256, 0, stream>>>(partial, embt, w_ih, b_ih, b_hh,
                                         out_W, out_b, out);
}